// Round 1
// baseline (192.168 us; speedup 1.0000x reference)
//
#include <hip/hip_runtime.h>
#include <math.h>

#define N_NODES 50000
#define DEG 16
#define E_EDGES (N_NODES * DEG)
#define FIN 128
#define FTOT 192   // 2*FQK + FV
#define H 8

// ---------------- GEMM: qkv = x @ W  ([N,128] x [128,192]) ----------------
#define BM 64
#define BN 64
#define BK 32

__global__ __launch_bounds__(256) void gemm_qkv(const float* __restrict__ x,
                                                const float* __restrict__ W,
                                                float* __restrict__ qkv) {
    __shared__ float As[BK][BM + 1];
    __shared__ float Bs[BK][BN + 1];
    const int tid = threadIdx.x;
    const int bm0 = blockIdx.x * BM;
    const int bn0 = blockIdx.y * BN;
    const int ty = tid >> 4, tx = tid & 15;
    float acc[4][4] = {};

    for (int k0 = 0; k0 < FIN; k0 += BK) {
        // A tile: 64 rows x 32 k, transposed into As[k][m]
#pragma unroll
        for (int i = 0; i < 8; i++) {
            int idx = tid + i * 256;
            int r = idx >> 5, c = idx & 31;
            int row = bm0 + r;
            As[c][r] = (row < N_NODES) ? x[row * FIN + k0 + c] : 0.f;
        }
        // B tile: 32 k x 64 cols
#pragma unroll
        for (int i = 0; i < 8; i++) {
            int idx = tid + i * 256;
            int r = idx >> 6, c = idx & 63;
            Bs[r][c] = W[(k0 + r) * FTOT + bn0 + c];
        }
        __syncthreads();
#pragma unroll
        for (int k = 0; k < BK; k++) {
            float a[4], b[4];
#pragma unroll
            for (int i = 0; i < 4; i++) a[i] = As[k][ty * 4 + i];
#pragma unroll
            for (int j = 0; j < 4; j++) b[j] = Bs[k][tx * 4 + j];
#pragma unroll
            for (int i = 0; i < 4; i++)
#pragma unroll
                for (int j = 0; j < 4; j++)
                    acc[i][j] = fmaf(a[i], b[j], acc[i][j]);
        }
        __syncthreads();
    }
#pragma unroll
    for (int i = 0; i < 4; i++) {
        int row = bm0 + ty * 4 + i;
        if (row < N_NODES) {
#pragma unroll
            for (int j = 0; j < 4; j++)
                qkv[row * FTOT + bn0 + tx * 4 + j] = acc[i][j];
        }
    }
}

// ---------------- Attention: one wave (64 lanes = 8 heads x 8 dims) per node ----------------
// src = repeat(arange(N), 16): node n owns edges [n*16, n*16+16). Online softmax over 16 edges.
__global__ __launch_bounds__(256) void attn(const float* __restrict__ qkv,
                                            const int* __restrict__ dest,
                                            float* __restrict__ out) {
    const int node = blockIdx.x * 4 + (threadIdx.x >> 6);
    const int lane = threadIdx.x & 63;
    if (node >= N_NODES) return;  // wave-uniform (all 64 lanes share node)

    const float scaling = 0.35355339059327373f;  // (FQK/H)^-0.5 = 8^-0.5
    // lane = h*8 + f; q[node,h,f] = qkv[node*192 + lane]
    const float q = qkv[node * FTOT + lane] * scaling;
    const int* dst = dest + node * DEG;
    const int dj = dst[lane & 15];  // lanes 0..15 hold dest[0..15]

    float m = -INFINITY, s = 0.f, o = 0.f;
#pragma unroll
    for (int j = 0; j < DEG; j++) {
        const int d = __shfl(dj, j, 64);
        const float* base = qkv + d * FTOT;
        const float kk = base[64 + lane];    // k[d,h,f]
        const float vv = base[128 + lane];   // v[d,h,f]
        float l = q * kk;
        l += __shfl_xor(l, 1, 64);  // reduce over f (lane bits 0..2)
        l += __shfl_xor(l, 2, 64);
        l += __shfl_xor(l, 4, 64);
        const float mn = fmaxf(m, l);
        const float sc = __expf(m - mn);  // first iter: exp(-inf)=0
        const float p  = __expf(l - mn);
        s = s * sc + p;
        o = fmaf(o, sc, p * vv);
        m = mn;
    }
    out[node * 64 + lane] = o / s;
}

extern "C" void kernel_launch(void* const* d_in, const int* in_sizes, int n_in,
                              void* d_out, int out_size, void* d_ws, size_t ws_size,
                              hipStream_t stream) {
    const float* x = (const float*)d_in[0];
    const float* W = (const float*)d_in[1];
    // d_in[2] = batch (unused by reference)
    const int* ei = (const int*)d_in[3];
    const int* dest = ei + E_EDGES;  // ei[1]
    float* out = (float*)d_out;
    float* qkv = (float*)d_ws;       // 50000*192*4 = 38.4 MB scratch

    dim3 g1((N_NODES + BM - 1) / BM, FTOT / BN);
    gemm_qkv<<<g1, dim3(256), 0, stream>>>(x, W, qkv);
    attn<<<(N_NODES + 3) / 4, dim3(256), 0, stream>>>(qkv, dest, out);
}

// Round 2
// 124.775 us; speedup vs baseline: 1.5401x; 1.5401x over previous
//
#include <hip/hip_runtime.h>
#include <math.h>

#define N_NODES 50000
#define DEG 16
#define E_EDGES (N_NODES * DEG)
#define FIN 128
#define FTOT 192   // 2*FQK + FV
#define FQK 64
#define FV 64
#define H 8

typedef __attribute__((ext_vector_type(8))) short short8;
typedef __attribute__((ext_vector_type(4))) float float4v;

__device__ inline unsigned short f2bf(float f) {
    unsigned int u = __float_as_uint(f);
    unsigned int r = u + 0x7fffu + ((u >> 16) & 1u);  // RNE
    return (unsigned short)(r >> 16);
}
__device__ inline float bf2f(unsigned short b) {
    return __uint_as_float(((unsigned int)b) << 16);
}

// ---------- prep: Wt[n][k] = bf16(W[k][n]), n<192, k<128 ----------
__global__ void wt_prep(const float* __restrict__ W, unsigned short* __restrict__ Wt) {
    int t = blockIdx.x * 256 + threadIdx.x;
    if (t >= FIN * FTOT) return;
    int k = t / FTOT, n = t % FTOT;          // coalesced read of W
    Wt[n * FIN + k] = f2bf(W[t]);            // scattered u16 write (tiny)
}

// ---------- GEMM: qkv(bf16, kv-interleaved) = x @ W via MFMA ----------
// Block: 256 thr = 4 waves, 64 rows. Full K=128, full N=192 per block.
#define LDB 136   // 128 + 8 bf16 pad -> 2-way-only LDS conflicts
__global__ __launch_bounds__(256) void gemm_qkv(const float* __restrict__ x,
                                                const unsigned short* __restrict__ Wt,
                                                unsigned short* __restrict__ qkv) {
    __shared__ unsigned short Bt[FTOT * LDB];
    const int tid = threadIdx.x;

    // stage Wt (48 KB) -> LDS with pad; 3072 16B-chunks over 256 threads
#pragma unroll
    for (int i = 0; i < 12; i++) {
        int c = tid + i * 256;
        int n = c >> 4, off = (c & 15) * 8;   // 8 bf16 = 16 B
        *(uint4*)(&Bt[n * LDB + off]) = *(const uint4*)(Wt + n * FIN + off);
    }

    const int wave = tid >> 6, lane = tid & 63;
    const int m = lane & 15, q = lane >> 4;
    const int row = blockIdx.x * 64 + wave * 16 + m;
    const int rowc = min(row, N_NODES - 1);

    // A fragments: lane holds x[row][ s*32 + q*8 .. +7 ] for s=0..3
    short8 a[4];
    const float* xr = x + rowc * FIN;
#pragma unroll
    for (int s = 0; s < 4; s++) {
        float4v f0 = *(const float4v*)(xr + s * 32 + q * 8);
        float4v f1 = *(const float4v*)(xr + s * 32 + q * 8 + 4);
        short8 av;
        av[0] = (short)f2bf(f0.x); av[1] = (short)f2bf(f0.y);
        av[2] = (short)f2bf(f0.z); av[3] = (short)f2bf(f0.w);
        av[4] = (short)f2bf(f1.x); av[5] = (short)f2bf(f1.y);
        av[6] = (short)f2bf(f1.z); av[7] = (short)f2bf(f1.w);
        a[s] = av;
    }
    __syncthreads();

    const int drow0 = blockIdx.x * 64 + wave * 16 + q * 4;  // D rows for this lane
#pragma unroll
    for (int ct = 0; ct < 12; ct++) {
        float4v acc = {0.f, 0.f, 0.f, 0.f};
#pragma unroll
        for (int s = 0; s < 4; s++) {
            short8 b = *(const short8*)(&Bt[(ct * 16 + m) * LDB + s * 32 + q * 8]);
            acc = __builtin_amdgcn_mfma_f32_16x16x32_bf16(a[s], b, acc, 0, 0, 0);
        }
        // col -> interleaved offset; q gets pre-scaled
        const int col = ct * 16 + m;
        int off; float scale;
        if (col < FQK)            { off = col;                    scale = 0.35355339059327373f; }
        else if (col < 2 * FQK)   { off = 64 + 2 * (col - 64);    scale = 1.f; }  // k
        else                      { off = 64 + 2 * (col - 128) + 1; scale = 1.f; } // v
#pragma unroll
        for (int i = 0; i < 4; i++) {
            int r = drow0 + i;
            if (r < N_NODES) qkv[r * FTOT + off] = f2bf(acc[i] * scale);
        }
    }
}

// ---------- attention: one wave per node; kv gathered as one dword/lane/edge ----------
__global__ __launch_bounds__(256) void attn(const unsigned short* __restrict__ qkv,
                                            const int* __restrict__ dest,
                                            float* __restrict__ out) {
    const int node = blockIdx.x * 4 + (threadIdx.x >> 6);
    const int lane = threadIdx.x & 63;
    if (node >= N_NODES) return;  // wave-uniform

    const float qv = bf2f(qkv[node * FTOT + lane]);      // pre-scaled q
    const int dj = dest[node * DEG + (lane & 15)];       // lanes share cache line

    unsigned int kv[DEG];
#pragma unroll
    for (int j = 0; j < DEG; j++) {
        const int d = __shfl(dj, j, 64);
        kv[j] = *(const unsigned int*)(qkv + d * FTOT + 64 + 2 * lane);
    }

    float lg[DEG];
#pragma unroll
    for (int j = 0; j < DEG; j++) {
        float kf = __uint_as_float(kv[j] << 16);
        float l = qv * kf;
        l += __shfl_xor(l, 1, 64);   // reduce over f (lane bits 0..2)
        l += __shfl_xor(l, 2, 64);
        l += __shfl_xor(l, 4, 64);
        lg[j] = l;
    }
    float mx = lg[0];
#pragma unroll
    for (int j = 1; j < DEG; j++) mx = fmaxf(mx, lg[j]);
    float s = 0.f, o = 0.f;
#pragma unroll
    for (int j = 0; j < DEG; j++) {
        float p = __expf(lg[j] - mx);
        s += p;
        o = fmaf(p, __uint_as_float(kv[j] & 0xffff0000u), o);
    }
    out[node * 64 + lane] = o / s;
}

extern "C" void kernel_launch(void* const* d_in, const int* in_sizes, int n_in,
                              void* d_out, int out_size, void* d_ws, size_t ws_size,
                              hipStream_t stream) {
    const float* x = (const float*)d_in[0];
    const float* W = (const float*)d_in[1];
    // d_in[2] = batch (unused by reference)
    const int* ei = (const int*)d_in[3];
    const int* dest = ei + E_EDGES;  // ei[1]
    float* out = (float*)d_out;

    unsigned short* qkv = (unsigned short*)d_ws;                       // 19.2 MB
    unsigned short* Wt  = (unsigned short*)((char*)d_ws + 19200000);   // 48 KB

    wt_prep<<<(FIN * FTOT + 255) / 256, 256, 0, stream>>>(W, Wt);
    gemm_qkv<<<(N_NODES + 63) / 64, 256, 0, stream>>>(x, Wt, qkv);
    attn<<<(N_NODES + 3) / 4, 256, 0, stream>>>(qkv, dest, out);
}

// Round 3
// 112.889 us; speedup vs baseline: 1.7023x; 1.1053x over previous
//
#include <hip/hip_runtime.h>
#include <math.h>

#define N_NODES 50000
#define DEG 16
#define E_EDGES (N_NODES * DEG)
#define FIN 128
#define FTOT 192   // 2*FQK + FV
#define FQK 64
#define FV 64
#define H 8

typedef __attribute__((ext_vector_type(8))) short short8;
typedef __attribute__((ext_vector_type(4))) float float4v;

__device__ inline unsigned short f2bf(float f) {
    unsigned int u = __float_as_uint(f);
    unsigned int r = u + 0x7fffu + ((u >> 16) & 1u);  // RNE
    return (unsigned short)(r >> 16);
}
__device__ inline float bf2f(unsigned short b) {
    return __uint_as_float(((unsigned int)b) << 16);
}

// ---------- prep: Wt[n][k] = bf16(W[k][n]), n<192, k<128 ----------
__global__ void wt_prep(const float* __restrict__ W, unsigned short* __restrict__ Wt) {
    int t = blockIdx.x * 256 + threadIdx.x;
    if (t >= FIN * FTOT) return;
    int k = t / FTOT, n = t % FTOT;          // coalesced read of W
    Wt[n * FIN + k] = f2bf(W[t]);            // scattered u16 write (tiny)
}

// ---------- GEMM: qkv(bf16, kv-interleaved) = x @ W via MFMA ----------
// Block: 256 thr = 4 waves, 64 rows. Full K=128, full N=192 per block.
#define LDB 136   // 128 + 8 bf16 pad
#define LDC 194   // 192 + 2 bf16 pad for the epilogue transpose
__global__ __launch_bounds__(256) void gemm_qkv(const float* __restrict__ x,
                                                const unsigned short* __restrict__ Wt,
                                                unsigned short* __restrict__ qkv) {
    __shared__ unsigned short Bt[FTOT * LDB];           // 52224 B
    unsigned short* Ct = Bt;                            // reused after MFMAs (64*194=12416 u16)
    const int tid = threadIdx.x;

    // stage Wt (48 KB) -> LDS; 3072 16B-chunks over 256 threads
#pragma unroll
    for (int i = 0; i < 12; i++) {
        int c = tid + i * 256;
        int n = c >> 4, off = (c & 15) * 8;
        *(uint4*)(&Bt[n * LDB + off]) = *(const uint4*)(Wt + n * FIN + off);
    }

    const int wave = tid >> 6, lane = tid & 63;
    const int m = lane & 15, q = lane >> 4;
    const int row = blockIdx.x * 64 + wave * 16 + m;
    const int rowc = min(row, N_NODES - 1);

    // A fragments: lane holds x[row][ s*32 + q*8 .. +7 ]
    short8 a[4];
    const float* xr = x + rowc * FIN;
#pragma unroll
    for (int s = 0; s < 4; s++) {
        float4v f0 = *(const float4v*)(xr + s * 32 + q * 8);
        float4v f1 = *(const float4v*)(xr + s * 32 + q * 8 + 4);
        short8 av;
        av[0] = (short)f2bf(f0.x); av[1] = (short)f2bf(f0.y);
        av[2] = (short)f2bf(f0.z); av[3] = (short)f2bf(f0.w);
        av[4] = (short)f2bf(f1.x); av[5] = (short)f2bf(f1.y);
        av[6] = (short)f2bf(f1.z); av[7] = (short)f2bf(f1.w);
        a[s] = av;
    }
    __syncthreads();

    float4v acc[12];
#pragma unroll
    for (int ct = 0; ct < 12; ct++) acc[ct] = (float4v){0.f, 0.f, 0.f, 0.f};
#pragma unroll
    for (int ct = 0; ct < 12; ct++) {
#pragma unroll
        for (int s = 0; s < 4; s++) {
            short8 b = *(const short8*)(&Bt[(ct * 16 + m) * LDB + s * 32 + q * 8]);
            acc[ct] = __builtin_amdgcn_mfma_f32_16x16x32_bf16(a[s], b, acc[ct], 0, 0, 0);
        }
    }
    __syncthreads();   // all Bt reads done; safe to reuse as Ct

    // transpose into interleaved-layout LDS tile (q pre-scaled)
    const int lrow0 = wave * 16 + q * 4;
#pragma unroll
    for (int ct = 0; ct < 12; ct++) {
        const int col = ct * 16 + m;
        int off; float scale;
        if (col < FQK)          { off = col;                      scale = 0.35355339059327373f; }
        else if (col < 2 * FQK) { off = 64 + 2 * (col - 64);      scale = 1.f; }  // k
        else                    { off = 64 + 2 * (col - 128) + 1; scale = 1.f; }  // v
#pragma unroll
        for (int i = 0; i < 4; i++)
            Ct[(lrow0 + i) * LDC + off] = f2bf(acc[ct][i] * scale);
    }
    __syncthreads();

    // coalesced store: 64 rows x 96 dwords
    unsigned int* qg = (unsigned int*)qkv;
    const int base = blockIdx.x * 64;
#pragma unroll
    for (int i = 0; i < 24; i++) {
        int l = tid + i * 256;
        int r = l / 96, dw = l - r * 96;
        if (base + r < N_NODES)
            qg[(size_t)(base + r) * 96 + dw] = *(const unsigned int*)(&Ct[r * LDC + 2 * dw]);
    }
}

// ---------- attention: one wave per node; two wave-halves process two edges concurrently ----------
__global__ __launch_bounds__(256) void attn(const unsigned short* __restrict__ qkv,
                                            const int* __restrict__ dest,
                                            float* __restrict__ out) {
    const int node = blockIdx.x * 4 + (threadIdx.x >> 6);
    const int lane = threadIdx.x & 63;
    const int half = lane >> 5;
    const int l = lane & 31;           // owns slots 2l, 2l+1
    if (node >= N_NODES) return;       // wave-uniform

    const unsigned int qw = *(const unsigned int*)(qkv + node * FTOT + 2 * l);  // pre-scaled q
    const float q0 = bf2f((unsigned short)(qw & 0xffffu));
    const float q1 = bf2f((unsigned short)(qw >> 16));
    const int dj = dest[node * DEG + (lane & 15)];

    uint2 kv[8];
#pragma unroll
    for (int t = 0; t < 8; t++) {
        const int d = __shfl(dj, 2 * t + half, 64);
        kv[t] = *(const uint2*)(qkv + d * FTOT + 64 + 4 * l);  // k/v for slots 2l,2l+1
    }

    float lg[8];
#pragma unroll
    for (int t = 0; t < 8; t++) {
        const float k0 = bf2f((unsigned short)(kv[t].x & 0xffffu));
        const float k1 = bf2f((unsigned short)(kv[t].y & 0xffffu));
        float p = fmaf(q0, k0, q1 * k1);
        p += __shfl_xor(p, 1, 64);     // reduce over the head's 4 lanes
        p += __shfl_xor(p, 2, 64);
        lg[t] = p;
    }
    float mx = lg[0];
#pragma unroll
    for (int t = 1; t < 8; t++) mx = fmaxf(mx, lg[t]);
    float s = 0.f, o0 = 0.f, o1 = 0.f;
#pragma unroll
    for (int t = 0; t < 8; t++) {
        const float p = __expf(lg[t] - mx);
        s += p;
        o0 = fmaf(p, __uint_as_float(kv[t].x & 0xffff0000u), o0);
        o1 = fmaf(p, __uint_as_float(kv[t].y & 0xffff0000u), o1);
    }
    // merge the two halves (each covered 8 of the 16 edges)
    const float mo = __shfl_xor(mx, 32, 64);
    const float mn = fmaxf(mx, mo);
    const float f = __expf(mx - mn);
    s *= f; o0 *= f; o1 *= f;
    s  += __shfl_xor(s, 32, 64);
    o0 += __shfl_xor(o0, 32, 64);
    o1 += __shfl_xor(o1, 32, 64);
    if (half == 0) {
        float2 r; r.x = o0 / s; r.y = o1 / s;
        *(float2*)(out + node * 64 + 2 * l) = r;
    }
}

extern "C" void kernel_launch(void* const* d_in, const int* in_sizes, int n_in,
                              void* d_out, int out_size, void* d_ws, size_t ws_size,
                              hipStream_t stream) {
    const float* x = (const float*)d_in[0];
    const float* W = (const float*)d_in[1];
    // d_in[2] = batch (unused by reference)
    const int* ei = (const int*)d_in[3];
    const int* dest = ei + E_EDGES;  // ei[1]
    float* out = (float*)d_out;

    unsigned short* qkv = (unsigned short*)d_ws;                       // 19.2 MB
    unsigned short* Wt  = (unsigned short*)((char*)d_ws + 19200000);   // 48 KB

    wt_prep<<<(FIN * FTOT + 255) / 256, 256, 0, stream>>>(W, Wt);
    gemm_qkv<<<(N_NODES + 63) / 64, 256, 0, stream>>>(x, Wt, qkv);
    attn<<<(N_NODES + 3) / 4, 256, 0, stream>>>(qkv, dest, out);
}